// Round 19
// baseline (226.801 us; speedup 1.0000x reference)
//
#include <hip/hip_runtime.h>
#include <hip/hip_bf16.h>

// SDPA with bias, materializing output + attention weights.
// B=4, H=8, T=2048, DK=64, fp32 in/out, bf16 MFMA 16x16x32 inside.
// Round 19: r17 (best: 202us) + phase 1 goes BARRIER-FREE via fragment-
// ordered K (Kf prepass): each wave loads its 8 MFMA A-fragments per tile as
// 64-lane x 16B fully-contiguous instructions straight from global (the same
// transaction shape as staging loads -- fixing r2/r11's 16-row-scatter
// poison). Phase 1: no LDS, no barriers, free-running waves. l accumulation
// order unchanged -> bit-identical. Phase 2 byte-identical to r17 (staged
// LDS, soft barrier, NT W/O stores). No setprio (r18 lesson).
#define TT   2048
#define DKK  64
#define NHH  8
#define NBB  4
#define QB   128
#define KBLK 64
#define NKT  (TT / KBLK)   // 32
#define NJ1  (NKT / 2)     // 16 phase-1 iterations, 2 tiles each
#define LDE  72            // padded LDS row stride: 144B = 9x16B (b128-aligned)
#define TILE (KBLK * LDE)
#define SCALE 0.125f

// LDS-only barrier: waits own ds ops, syncs waves, does NOT drain vmcnt
#define SOFT_BARRIER() do {                                         \
    asm volatile("s_waitcnt lgkmcnt(0)" ::: "memory");              \
    __builtin_amdgcn_s_barrier();                                   \
    asm volatile("" ::: "memory");                                  \
} while (0)

typedef __attribute__((ext_vector_type(4))) float  f32x4;
typedef __attribute__((ext_vector_type(8))) __bf16 bf16x8;
typedef __attribute__((ext_vector_type(4))) __bf16 bf16x4;

// ---- prepass 1: K fp32 -> bf16, same [bh][t][d] layout (phase 2) ----
__global__ __launch_bounds__(256)
void cast_k_kernel(const float* __restrict__ K, __bf16* __restrict__ Kb) {
    size_t i = ((size_t)blockIdx.x * 256 + threadIdx.x) * 8;
    f32x4 a = *(const f32x4*)(K + i);
    f32x4 b = *(const f32x4*)(K + i + 4);
    bf16x8 o = {(__bf16)a[0], (__bf16)a[1], (__bf16)a[2], (__bf16)a[3],
                (__bf16)b[0], (__bf16)b[1], (__bf16)b[2], (__bf16)b[3]};
    *(bf16x8*)(Kb + i) = o;
}

// ---- prepass 1b: K fp32 -> fragment-ordered bf16 Kf (phase 1) ----
// Kf[bh][kt][frag = s*2+hh][lane][8]: lane (ql=lane&15, g=lane>>4) holds
// K[kt*64 + s*16 + ql][hh*32 + g*8 .. +7]. Wave frag-load = 1KB contiguous.
__global__ __launch_bounds__(512)
void kf_kernel(const float* __restrict__ K, __bf16* __restrict__ Kf) {
    const int bh  = blockIdx.y;        // 0..31
    const int kt  = blockIdx.x;        // 0..31
    const int tid = threadIdx.x;       // 512 = s(4) x hh(2) x lane(64)
    const int s    = tid >> 7;
    const int hh   = (tid >> 6) & 1;
    const int lane = tid & 63;
    const int ql = lane & 15, g = lane >> 4;
    const float* src = K + ((size_t)bh * TT + kt * KBLK + s * 16 + ql) * DKK
                         + hh * 32 + g * 8;
    f32x4 x = *(const f32x4*)(src);
    f32x4 y = *(const f32x4*)(src + 4);
    bf16x8 o = {(__bf16)x[0], (__bf16)x[1], (__bf16)x[2], (__bf16)x[3],
                (__bf16)y[0], (__bf16)y[1], (__bf16)y[2], (__bf16)y[3]};
    *(bf16x8*)(Kf + ((size_t)(bh * NKT + kt) * 4096) + (size_t)tid * 8) = o;
}

// ---- prepass 2: V fp32 [bh][t][d] -> bf16 transposed [bh][d][t] ----
__global__ __launch_bounds__(256)
void vt_kernel(const float* __restrict__ V, __bf16* __restrict__ Vt) {
    __shared__ __bf16 tile[DKK][72];
    const int bh = blockIdx.y;
    const int t0 = blockIdx.x * 64;
    const int tid = threadIdx.x;
    const float* Vb = V + ((size_t)bh * TT + t0) * DKK;
    #pragma unroll
    for (int i = 0; i < 4; ++i) {
        int idx = tid + i * 256;
        int row = idx >> 4, c4 = idx & 15;
        f32x4 v = *(const f32x4*)(Vb + row * DKK + c4 * 4);
        tile[c4 * 4 + 0][row] = (__bf16)v[0];
        tile[c4 * 4 + 1][row] = (__bf16)v[1];
        tile[c4 * 4 + 2][row] = (__bf16)v[2];
        tile[c4 * 4 + 3][row] = (__bf16)v[3];
    }
    __syncthreads();
    __bf16* out = Vt + (size_t)bh * DKK * TT + t0;
    #pragma unroll
    for (int i = 0; i < 2; ++i) {
        int idx = tid + i * 256;
        int d = idx >> 3, ch = idx & 7;
        bf16x8 o = *(const bf16x8*)&tile[d][ch * 8];
        *(bf16x8*)(out + (size_t)d * TT + ch * 8) = o;
    }
}

// ---- main: 8 q-waves, 128 q-rows/block ----
__global__ __launch_bounds__(512, 4)
void sdpa_main(const float* __restrict__ Qp, const float* __restrict__ Bp,
               const __bf16* __restrict__ Kb, const __bf16* __restrict__ Vt,
               const __bf16* __restrict__ Kf,
               float* __restrict__ Op, float* __restrict__ Wp)
{
    __shared__ __bf16 Bl[4][TILE];     // phase 2 only: [0..1]=K dbuf, [2..3]=V dbuf
    __shared__ __bf16 Pl[8][16 * LDE]; // wave-private P [q][key]

    const int tid  = threadIdx.x;
    const int lane = tid & 63;
    const int w    = tid >> 6;     // 0..7 : q rows w*16..+15
    const int g    = lane >> 4;    // 0..3
    const int ql   = lane & 15;

    // XCD-aware decode: h = id&7 pins each head's bias slice to one XCD.
    const int id  = blockIdx.x;    // 0..511
    const int h   = id & 7;
    const int r   = id >> 3;       // 0..63
    const int qt  = r & 15;        // 0..15
    const int b   = r >> 4;        // 0..3
    const int bh  = b * NHH + h;

    const int q_local = w * 16 + ql;
    const int q_glob  = qt * QB + q_local;

    const __bf16* Kbh = Kb + (size_t)bh * TT * DKK;   // [key][d]
    const __bf16* Vbh = Vt + (size_t)bh * DKK * TT;   // [d][key]
    const __bf16* Kfb = Kf + (size_t)bh * NKT * 4096; // fragment-ordered
    const float* biasRow = Bp + ((size_t)h * TT + q_glob) * TT;

    // staging map (phase 2): 512 threads x 16B = one 64x64 bf16 tile
    const int srow = tid >> 3;     // 0..63
    const int sch  = tid & 7;      // 0..7

    // Q fragments (B-operand): lane holds Q[q_glob][d = 8g+j (+32)]
    const float* qrow = Qp + ((size_t)bh * TT + q_glob) * DKK;
    f32x4 qa = *(const f32x4*)(qrow + g * 8);
    f32x4 qc = *(const f32x4*)(qrow + g * 8 + 4);
    f32x4 qe = *(const f32x4*)(qrow + 32 + g * 8);
    f32x4 qf = *(const f32x4*)(qrow + 32 + g * 8 + 4);
    const bf16x8 qfrag0 = {(__bf16)qa[0], (__bf16)qa[1], (__bf16)qa[2], (__bf16)qa[3],
                           (__bf16)qc[0], (__bf16)qc[1], (__bf16)qc[2], (__bf16)qc[3]};
    const bf16x8 qfrag1 = {(__bf16)qe[0], (__bf16)qe[1], (__bf16)qe[2], (__bf16)qe[3],
                           (__bf16)qf[0], (__bf16)qf[1], (__bf16)qf[2], (__bf16)qf[3]};

    // ========== phase 1: l = sum exp(s) -- barrier-free, LDS-free ========
    // Each wave streams its own fragment loads (1KB coalesced per instr).
    f32x4 lacc = {0.f, 0.f, 0.f, 0.f};
    for (int j = 0; j < NJ1; ++j) {
        #pragma unroll
        for (int t = 0; t < 2; ++t) {
            const int kt = j * 2 + t;
            const __bf16* kf = Kfb + (size_t)kt * 4096 + lane * 8;
            bf16x8 a[8];
            #pragma unroll
            for (int f = 0; f < 8; ++f)
                a[f] = *(const bf16x8*)(kf + f * 512);
            const float* bp = biasRow + kt * KBLK;
            f32x4 bv[4];
            #pragma unroll
            for (int s = 0; s < 4; ++s) bv[s] = *(const f32x4*)(bp + s * 16 + g * 4);
            f32x4 acc[4] = {};
            #pragma unroll
            for (int s = 0; s < 4; ++s) {
                acc[s] = __builtin_amdgcn_mfma_f32_16x16x32_bf16(a[s * 2],     qfrag0, acc[s], 0, 0, 0);
                acc[s] = __builtin_amdgcn_mfma_f32_16x16x32_bf16(a[s * 2 + 1], qfrag1, acc[s], 0, 0, 0);
            }
            #pragma unroll
            for (int s = 0; s < 4; ++s) {
                f32x4 x = acc[s] * SCALE + bv[s];
                lacc[0] += __expf(x[0]);
                lacc[1] += __expf(x[1]);
                lacc[2] += __expf(x[2]);
                lacc[3] += __expf(x[3]);
            }
        }
    }
    float l_run = lacc[0] + lacc[1] + lacc[2] + lacc[3];
    l_run += __shfl_xor(l_run, 16);
    l_run += __shfl_xor(l_run, 32);
    const float inv_l = 1.0f / l_run;

    // ================= phase 2: recompute, write W, accumulate PV ========
    // (byte-identical to r17) buffers: Bl[0..1]=K dbuf, Bl[2..3]=V dbuf
    *(bf16x8*)&Bl[0][srow * LDE + sch * 8] =
        *(const bf16x8*)(Kbh + (size_t)srow * DKK + sch * 8);
    *(bf16x8*)&Bl[2][srow * LDE + sch * 8] =
        *(const bf16x8*)(Vbh + (size_t)srow * TT + sch * 8);
    __syncthreads();

    f32x4 oacc[4] = {};            // O^T[d = m*16+4g+r][q_local]
    for (int kt = 0; kt < NKT; ++kt) {
        const int cur = kt & 1;
        const bool more = (kt + 1 < NKT);
        bf16x8 kreg, vreg;
        if (more) {
            kreg = *(const bf16x8*)(Kbh + ((size_t)(kt + 1) * KBLK + srow) * DKK + sch * 8);
            vreg = *(const bf16x8*)(Vbh + (size_t)srow * TT + (kt + 1) * KBLK + sch * 8);
        }
        const float* bp = biasRow + kt * KBLK;
        f32x4 bv[4];
        #pragma unroll
        for (int s = 0; s < 4; ++s) bv[s] = *(const f32x4*)(bp + s * 16 + g * 4);

        f32x4 acc[4] = {};
        #pragma unroll
        for (int s = 0; s < 4; ++s) {
            bf16x8 a0 = *(const bf16x8*)&Bl[cur][(s * 16 + ql) * LDE + g * 8];
            acc[s] = __builtin_amdgcn_mfma_f32_16x16x32_bf16(a0, qfrag0, acc[s], 0, 0, 0);
            bf16x8 a1 = *(const bf16x8*)&Bl[cur][(s * 16 + ql) * LDE + 32 + g * 8];
            acc[s] = __builtin_amdgcn_mfma_f32_16x16x32_bf16(a1, qfrag1, acc[s], 0, 0, 0);
        }
        // P = softmax weights (bf16), wave-private tile
        #pragma unroll
        for (int s = 0; s < 4; ++s) {
            f32x4 x = acc[s] * SCALE + bv[s];
            bf16x4 pb = {(__bf16)(__expf(x[0]) * inv_l), (__bf16)(__expf(x[1]) * inv_l),
                         (__bf16)(__expf(x[2]) * inv_l), (__bf16)(__expf(x[3]) * inv_l)};
            *(bf16x4*)&Pl[w][ql * LDE + s * 16 + g * 4] = pb;
        }
        // PV: read own wave's P fragments (same-wave DS RAW is in-order)
        const bf16x8 bp0 = *(const bf16x8*)&Pl[w][ql * LDE + g * 8];
        const bf16x8 bp1 = *(const bf16x8*)&Pl[w][ql * LDE + 32 + g * 8];
        #pragma unroll
        for (int m = 0; m < 4; ++m) {
            bf16x8 av0 = *(const bf16x8*)&Bl[2 + cur][(m * 16 + ql) * LDE + g * 8];
            oacc[m] = __builtin_amdgcn_mfma_f32_16x16x32_bf16(av0, bp0, oacc[m], 0, 0, 0);
            bf16x8 av1 = *(const bf16x8*)&Bl[2 + cur][(m * 16 + ql) * LDE + 32 + g * 8];
            oacc[m] = __builtin_amdgcn_mfma_f32_16x16x32_bf16(av1, bp1, oacc[m], 0, 0, 0);
        }
        // cooperative W store from Pl: 4 rows x 256B per instr, NONTEMPORAL
        #pragma unroll
        for (int s2 = 0; s2 < 4; ++s2) {
            const int wr = s2 * 4 + g;                 // row 0..15 within wave
            bf16x4 pw = *(const bf16x4*)&Pl[w][wr * LDE + ql * 4];
            f32x4 ow = {(float)pw[0], (float)pw[1], (float)pw[2], (float)pw[3]};
            __builtin_nontemporal_store(ow,
                (f32x4*)(Wp + ((size_t)bh * TT + qt * QB + w * 16 + wr) * TT
                             + kt * KBLK + ql * 4));
        }
        if (more) {  // write-late staging into cur^1 (WAR-safe), then barrier
            *(bf16x8*)&Bl[cur ^ 1][srow * LDE + sch * 8] = kreg;
            *(bf16x8*)&Bl[2 + (cur ^ 1)][srow * LDE + sch * 8] = vreg;
        }
        SOFT_BARRIER();
    }

    // ---- store O (nontemporal; write-once) ----
    float* Orow = Op + ((size_t)bh * TT + q_glob) * DKK;
    #pragma unroll
    for (int m = 0; m < 4; ++m)
        __builtin_nontemporal_store(oacc[m], (f32x4*)(Orow + m * 16 + g * 4));
}

extern "C" void kernel_launch(void* const* d_in, const int* in_sizes, int n_in,
                              void* d_out, int out_size, void* d_ws, size_t ws_size,
                              hipStream_t stream) {
    const float* Q  = (const float*)d_in[0];
    const float* K  = (const float*)d_in[1];
    const float* V  = (const float*)d_in[2];
    const float* Bs = (const float*)d_in[3];
    float* Out = (float*)d_out;
    float* W   = Out + (size_t)NBB * NHH * TT * DKK;

    const size_t nElem = (size_t)NBB * NHH * TT * DKK;   // 4,194,304
    __bf16* Kb = (__bf16*)d_ws;                          // 8 MB
    __bf16* Vt = Kb + nElem;                             // 8 MB
    __bf16* Kf = Vt + nElem;                             // 8 MB (fragment order)

    cast_k_kernel<<<dim3(nElem / 8 / 256), dim3(256), 0, stream>>>(K, Kb);
    kf_kernel<<<dim3(NKT, NBB * NHH), dim3(512), 0, stream>>>(K, Kf);
    vt_kernel<<<dim3(TT / 64, NBB * NHH), dim3(256), 0, stream>>>(V, Vt);
    sdpa_main<<<dim3((TT / QB) * NBB * NHH), dim3(512), 0, stream>>>(Q, Bs, Kb, Vt, Kf, Out, W);
}

// Round 20
// 202.579 us; speedup vs baseline: 1.1196x; 1.1196x over previous
//
#include <hip/hip_runtime.h>
#include <hip/hip_bf16.h>

// SDPA with bias, materializing output + attention weights.
// B=4, H=8, T=2048, DK=64, fp32 in/out, bf16 MFMA 16x16x32 inside.
// FINAL (= round 17, session best: 202us). Structure and why:
//  - Two-phase (l-sum, then recompute+normalize): normalized W (512MB) forces
//    two K-sweeps; recompute beats caching S (traffic arithmetic).
//  - 8 q-waves x 128 q-rows/block; K & V^T tiles LDS-staged coalesced,
//    double-buffered, ONE soft barrier (lgkmcnt-only) per 64-key step.
//    (r2/r6/r11/r19: any scattered-fragment direct-global load = +80us.)
//  - Phase 1: 2 tiles/iter pair ping-pong (WAR-safe write-late prefetch).
//  - NT stores on W and O: keeps the dead 512MB write stream out of L2/L3 so
//    bias/K/V stay cache-resident (r13: -58us; r12's FETCH blowup was this).
//  - No setprio (r18: -4us), no extra occupancy (r4/r7/r14: null x3).
#define TT   2048
#define DKK  64
#define NHH  8
#define NBB  4
#define QB   128
#define KBLK 64
#define NKT  (TT / KBLK)   // 32
#define NJ1  (NKT / 2)     // 16 phase-1 iterations, 2 tiles each
#define LDE  72            // padded LDS row stride: 144B = 9x16B (b128-aligned)
#define TILE (KBLK * LDE)
#define SCALE 0.125f

// LDS-only barrier: waits own ds ops, syncs waves, does NOT drain vmcnt
#define SOFT_BARRIER() do {                                         \
    asm volatile("s_waitcnt lgkmcnt(0)" ::: "memory");              \
    __builtin_amdgcn_s_barrier();                                   \
    asm volatile("" ::: "memory");                                  \
} while (0)

typedef __attribute__((ext_vector_type(4))) float  f32x4;
typedef __attribute__((ext_vector_type(8))) __bf16 bf16x8;
typedef __attribute__((ext_vector_type(4))) __bf16 bf16x4;

// ---- prepass 1: K fp32 -> bf16, same [bh][t][d] layout ----
__global__ __launch_bounds__(256)
void cast_k_kernel(const float* __restrict__ K, __bf16* __restrict__ Kb) {
    size_t i = ((size_t)blockIdx.x * 256 + threadIdx.x) * 8;
    f32x4 a = *(const f32x4*)(K + i);
    f32x4 b = *(const f32x4*)(K + i + 4);
    bf16x8 o = {(__bf16)a[0], (__bf16)a[1], (__bf16)a[2], (__bf16)a[3],
                (__bf16)b[0], (__bf16)b[1], (__bf16)b[2], (__bf16)b[3]};
    *(bf16x8*)(Kb + i) = o;
}

// ---- prepass 2: V fp32 [bh][t][d] -> bf16 transposed [bh][d][t] ----
__global__ __launch_bounds__(256)
void vt_kernel(const float* __restrict__ V, __bf16* __restrict__ Vt) {
    __shared__ __bf16 tile[DKK][72];
    const int bh = blockIdx.y;
    const int t0 = blockIdx.x * 64;
    const int tid = threadIdx.x;
    const float* Vb = V + ((size_t)bh * TT + t0) * DKK;
    #pragma unroll
    for (int i = 0; i < 4; ++i) {
        int idx = tid + i * 256;
        int row = idx >> 4, c4 = idx & 15;
        f32x4 v = *(const f32x4*)(Vb + row * DKK + c4 * 4);
        tile[c4 * 4 + 0][row] = (__bf16)v[0];
        tile[c4 * 4 + 1][row] = (__bf16)v[1];
        tile[c4 * 4 + 2][row] = (__bf16)v[2];
        tile[c4 * 4 + 3][row] = (__bf16)v[3];
    }
    __syncthreads();
    __bf16* out = Vt + (size_t)bh * DKK * TT + t0;
    #pragma unroll
    for (int i = 0; i < 2; ++i) {
        int idx = tid + i * 256;
        int d = idx >> 3, ch = idx & 7;
        bf16x8 o = *(const bf16x8*)&tile[d][ch * 8];
        *(bf16x8*)(out + (size_t)d * TT + ch * 8) = o;
    }
}

// ---- main: 8 q-waves, 128 q-rows/block ----
__global__ __launch_bounds__(512, 4)
void sdpa_main(const float* __restrict__ Qp, const float* __restrict__ Bp,
               const __bf16* __restrict__ Kb, const __bf16* __restrict__ Vt,
               float* __restrict__ Op, float* __restrict__ Wp)
{
    __shared__ __bf16 Bl[4][TILE];     // ph1: two K pairs; ph2: [0..1]=K, [2..3]=V
    __shared__ __bf16 Pl[8][16 * LDE]; // wave-private P [q][key]

    const int tid  = threadIdx.x;
    const int lane = tid & 63;
    const int w    = tid >> 6;     // 0..7 : q rows w*16..+15
    const int g    = lane >> 4;    // 0..3
    const int ql   = lane & 15;

    // XCD-aware decode: h = id&7 pins each head's bias slice to one XCD.
    const int id  = blockIdx.x;    // 0..511
    const int h   = id & 7;
    const int r   = id >> 3;       // 0..63
    const int qt  = r & 15;        // 0..15
    const int b   = r >> 4;        // 0..3
    const int bh  = b * NHH + h;

    const int q_local = w * 16 + ql;
    const int q_glob  = qt * QB + q_local;

    const __bf16* Kbh = Kb + (size_t)bh * TT * DKK;   // [key][d]
    const __bf16* Vbh = Vt + (size_t)bh * DKK * TT;   // [d][key]
    const float* biasRow = Bp + ((size_t)h * TT + q_glob) * TT;

    // staging map: 512 threads x 16B = one 64x64 bf16 tile
    const int srow = tid >> 3;     // 0..63
    const int sch  = tid & 7;      // 0..7

    // Q fragments (B-operand): lane holds Q[q_glob][d = 8g+j (+32)]
    const float* qrow = Qp + ((size_t)bh * TT + q_glob) * DKK;
    f32x4 qa = *(const f32x4*)(qrow + g * 8);
    f32x4 qc = *(const f32x4*)(qrow + g * 8 + 4);
    f32x4 qe = *(const f32x4*)(qrow + 32 + g * 8);
    f32x4 qf = *(const f32x4*)(qrow + 32 + g * 8 + 4);
    const bf16x8 qfrag0 = {(__bf16)qa[0], (__bf16)qa[1], (__bf16)qa[2], (__bf16)qa[3],
                           (__bf16)qc[0], (__bf16)qc[1], (__bf16)qc[2], (__bf16)qc[3]};
    const bf16x8 qfrag1 = {(__bf16)qe[0], (__bf16)qe[1], (__bf16)qe[2], (__bf16)qe[3],
                           (__bf16)qf[0], (__bf16)qf[1], (__bf16)qf[2], (__bf16)qf[3]};

    // ========== phase 1: l = sum exp(s); 2 tiles/iter, pair ping-pong =====
    #pragma unroll
    for (int t = 0; t < 2; ++t) {
        *(bf16x8*)&Bl[t][srow * LDE + sch * 8] =
            *(const bf16x8*)(Kbh + ((size_t)t * KBLK + srow) * DKK + sch * 8);
    }
    __syncthreads();

    f32x4 lacc = {0.f, 0.f, 0.f, 0.f};
    for (int j = 0; j < NJ1; ++j) {
        const int pc = (j & 1) * 2;        // pair being read this iteration
        const int pn = ((j + 1) & 1) * 2;  // pair to fill for next iteration
        const bool more = (j + 1 < NJ1);
        bf16x8 kregs[2];
        if (more) {   // 2-deep prefetch (2x MLP on the latency path)
            #pragma unroll
            for (int t = 0; t < 2; ++t)
                kregs[t] = *(const bf16x8*)(Kbh +
                    ((size_t)((j + 1) * 2 + t) * KBLK + srow) * DKK + sch * 8);
        }
        #pragma unroll
        for (int t = 0; t < 2; ++t) {
            const int kt = j * 2 + t;
            const float* bp = biasRow + kt * KBLK;
            f32x4 bv[4];
            #pragma unroll
            for (int s = 0; s < 4; ++s) bv[s] = *(const f32x4*)(bp + s * 16 + g * 4);
            f32x4 acc[4] = {};
            #pragma unroll
            for (int s = 0; s < 4; ++s) {
                bf16x8 a0 = *(const bf16x8*)&Bl[pc + t][(s * 16 + ql) * LDE + g * 8];
                acc[s] = __builtin_amdgcn_mfma_f32_16x16x32_bf16(a0, qfrag0, acc[s], 0, 0, 0);
                bf16x8 a1 = *(const bf16x8*)&Bl[pc + t][(s * 16 + ql) * LDE + 32 + g * 8];
                acc[s] = __builtin_amdgcn_mfma_f32_16x16x32_bf16(a1, qfrag1, acc[s], 0, 0, 0);
            }
            #pragma unroll
            for (int s = 0; s < 4; ++s) {
                f32x4 x = acc[s] * SCALE + bv[s];
                lacc[0] += __expf(x[0]);
                lacc[1] += __expf(x[1]);
                lacc[2] += __expf(x[2]);
                lacc[3] += __expf(x[3]);
            }
        }
        if (more) {   // write-late into the OTHER pair (reads of it retired
                      // at the previous barrier) -- WAR-safe like r5
            #pragma unroll
            for (int t = 0; t < 2; ++t)
                *(bf16x8*)&Bl[pn + t][srow * LDE + sch * 8] = kregs[t];
        }
        SOFT_BARRIER();
    }
    float l_run = lacc[0] + lacc[1] + lacc[2] + lacc[3];
    l_run += __shfl_xor(l_run, 16);
    l_run += __shfl_xor(l_run, 32);
    const float inv_l = 1.0f / l_run;

    // ================= phase 2: recompute, write W, accumulate PV ========
    // buffers: Bl[0..1] = K double buffer, Bl[2..3] = V^T double buffer
    __syncthreads();               // all phase-1 reads done before restaging
    *(bf16x8*)&Bl[0][srow * LDE + sch * 8] =
        *(const bf16x8*)(Kbh + (size_t)srow * DKK + sch * 8);
    *(bf16x8*)&Bl[2][srow * LDE + sch * 8] =
        *(const bf16x8*)(Vbh + (size_t)srow * TT + sch * 8);
    __syncthreads();

    f32x4 oacc[4] = {};            // O^T[d = m*16+4g+r][q_local]
    for (int kt = 0; kt < NKT; ++kt) {
        const int cur = kt & 1;
        const bool more = (kt + 1 < NKT);
        bf16x8 kreg, vreg;
        if (more) {
            kreg = *(const bf16x8*)(Kbh + ((size_t)(kt + 1) * KBLK + srow) * DKK + sch * 8);
            vreg = *(const bf16x8*)(Vbh + (size_t)srow * TT + (kt + 1) * KBLK + sch * 8);
        }
        const float* bp = biasRow + kt * KBLK;
        f32x4 bv[4];
        #pragma unroll
        for (int s = 0; s < 4; ++s) bv[s] = *(const f32x4*)(bp + s * 16 + g * 4);

        f32x4 acc[4] = {};
        #pragma unroll
        for (int s = 0; s < 4; ++s) {
            bf16x8 a0 = *(const bf16x8*)&Bl[cur][(s * 16 + ql) * LDE + g * 8];
            acc[s] = __builtin_amdgcn_mfma_f32_16x16x32_bf16(a0, qfrag0, acc[s], 0, 0, 0);
            bf16x8 a1 = *(const bf16x8*)&Bl[cur][(s * 16 + ql) * LDE + 32 + g * 8];
            acc[s] = __builtin_amdgcn_mfma_f32_16x16x32_bf16(a1, qfrag1, acc[s], 0, 0, 0);
        }
        // P = softmax weights (bf16), wave-private tile
        #pragma unroll
        for (int s = 0; s < 4; ++s) {
            f32x4 x = acc[s] * SCALE + bv[s];
            bf16x4 pb = {(__bf16)(__expf(x[0]) * inv_l), (__bf16)(__expf(x[1]) * inv_l),
                         (__bf16)(__expf(x[2]) * inv_l), (__bf16)(__expf(x[3]) * inv_l)};
            *(bf16x4*)&Pl[w][ql * LDE + s * 16 + g * 4] = pb;
        }
        // PV: read own wave's P fragments (same-wave DS RAW is in-order)
        const bf16x8 bp0 = *(const bf16x8*)&Pl[w][ql * LDE + g * 8];
        const bf16x8 bp1 = *(const bf16x8*)&Pl[w][ql * LDE + 32 + g * 8];
        #pragma unroll
        for (int m = 0; m < 4; ++m) {
            bf16x8 av0 = *(const bf16x8*)&Bl[2 + cur][(m * 16 + ql) * LDE + g * 8];
            oacc[m] = __builtin_amdgcn_mfma_f32_16x16x32_bf16(av0, bp0, oacc[m], 0, 0, 0);
            bf16x8 av1 = *(const bf16x8*)&Bl[2 + cur][(m * 16 + ql) * LDE + 32 + g * 8];
            oacc[m] = __builtin_amdgcn_mfma_f32_16x16x32_bf16(av1, bp1, oacc[m], 0, 0, 0);
        }
        // cooperative W store from Pl: 4 rows x 256B per instr, NONTEMPORAL
        #pragma unroll
        for (int s2 = 0; s2 < 4; ++s2) {
            const int wr = s2 * 4 + g;                 // row 0..15 within wave
            bf16x4 pw = *(const bf16x4*)&Pl[w][wr * LDE + ql * 4];
            f32x4 ow = {(float)pw[0], (float)pw[1], (float)pw[2], (float)pw[3]};
            __builtin_nontemporal_store(ow,
                (f32x4*)(Wp + ((size_t)bh * TT + qt * QB + w * 16 + wr) * TT
                             + kt * KBLK + ql * 4));
        }
        if (more) {  // write-late staging into cur^1 (WAR-safe), then barrier
            *(bf16x8*)&Bl[cur ^ 1][srow * LDE + sch * 8] = kreg;
            *(bf16x8*)&Bl[2 + (cur ^ 1)][srow * LDE + sch * 8] = vreg;
        }
        SOFT_BARRIER();
    }

    // ---- store O (nontemporal; write-once) ----
    float* Orow = Op + ((size_t)bh * TT + q_glob) * DKK;
    #pragma unroll
    for (int m = 0; m < 4; ++m)
        __builtin_nontemporal_store(oacc[m], (f32x4*)(Orow + m * 16 + g * 4));
}

extern "C" void kernel_launch(void* const* d_in, const int* in_sizes, int n_in,
                              void* d_out, int out_size, void* d_ws, size_t ws_size,
                              hipStream_t stream) {
    const float* Q  = (const float*)d_in[0];
    const float* K  = (const float*)d_in[1];
    const float* V  = (const float*)d_in[2];
    const float* Bs = (const float*)d_in[3];
    float* Out = (float*)d_out;
    float* W   = Out + (size_t)NBB * NHH * TT * DKK;

    const size_t nElem = (size_t)NBB * NHH * TT * DKK;
    __bf16* Kb = (__bf16*)d_ws;
    __bf16* Vt = Kb + nElem;

    cast_k_kernel<<<dim3(nElem / 8 / 256), dim3(256), 0, stream>>>(K, Kb);
    vt_kernel<<<dim3(TT / 64, NBB * NHH), dim3(256), 0, stream>>>(V, Vt);
    sdpa_main<<<dim3((TT / QB) * NBB * NHH), dim3(512), 0, stream>>>(Q, Bs, Kb, Vt, Out, W);
}